// Round 1
// baseline (107.916 us; speedup 1.0000x reference)
//
#include <hip/hip_runtime.h>

// EncoderRNN: 1-token, batch-1, bidirectional 2-layer LSTM. H=2048, EMB=1024.
// Memory-bound mat-vec: one wave (64 lanes) per gate row, float4 loads,
// shuffle reduction. Small cell kernel applies activations.

#define HID 2048
#define G4H 8192   // 4*HID rows per direction

__device__ __forceinline__ float wave_reduce_sum(float v) {
    #pragma unroll
    for (int off = 32; off > 0; off >>= 1)
        v += __shfl_down(v, off, 64);
    return v;
}

// gates[dir][r] = dot(Wih[dir][r], x) + bih[dir][r] + dot(Whh[dir][r], h0[h0_off+dir]) + bhh[dir][r]
template<int XDIM>
__global__ __launch_bounds__(256) void gates_kernel(
    const float* __restrict__ x,      // [XDIM] (shared by both directions)
    const int*   __restrict__ tok,    // if non-null: x += tok[0]*XDIM (embedding row)
    const float* __restrict__ Wih,    // [2][8192][XDIM]
    const float* __restrict__ Whh,    // [2][8192][HID]
    const float* __restrict__ bih,    // [2][8192]
    const float* __restrict__ bhh,    // [2][8192]
    const float* __restrict__ h0,     // [4][HID]
    int h0_off,                       // 0 (layer 0) or 2 (layer 1)
    float* __restrict__ gates)        // [2][8192]
{
    const int wave = (int)((blockIdx.x * blockDim.x + threadIdx.x) >> 6);
    const int lane = (int)(threadIdx.x & 63);
    const int dir  = wave >> 13;        // 0..1
    const int r    = wave & (G4H - 1);  // 0..8191

    if (tok) x += (size_t)tok[0] * XDIM;

    const float4* wih = (const float4*)(Wih + ((size_t)dir * G4H + r) * XDIM);
    const float4* whh = (const float4*)(Whh + ((size_t)dir * G4H + r) * HID);
    const float4* xv  = (const float4*)x;
    const float4* hv  = (const float4*)(h0 + (size_t)(h0_off + dir) * HID);

    float acc = 0.f;
    #pragma unroll
    for (int i = 0; i < XDIM / 4 / 64; ++i) {
        float4 w = wih[lane + i * 64];
        float4 b = xv [lane + i * 64];
        acc += w.x * b.x + w.y * b.y + w.z * b.z + w.w * b.w;
    }
    #pragma unroll
    for (int i = 0; i < HID / 4 / 64; ++i) {
        float4 w = whh[lane + i * 64];
        float4 b = hv [lane + i * 64];
        acc += w.x * b.x + w.y * b.y + w.z * b.z + w.w * b.w;
    }
    acc = wave_reduce_sum(acc);
    if (lane == 0) {
        int row = dir * G4H + r;
        gates[row] = acc + bih[row] + bhh[row];
    }
}

__device__ __forceinline__ float sigmoidf_(float v) {
    return 1.f / (1.f + expf(-v));
}

// PyTorch gate order i,f,g,o: i=g[0:H], f=g[H:2H], g=g[2H:3H], o=g[3H:4H]
__global__ __launch_bounds__(256) void cell_kernel(
    const float* __restrict__ gates,  // [2][8192]
    const float* __restrict__ c0,     // [4][HID]
    int lo,                           // 0 (layer 0) or 2 (layer 1)
    float* __restrict__ hn,           // d_out + 4096  -> [4][HID]
    float* __restrict__ cn,           // d_out + 12288 -> [4][HID]
    float* __restrict__ xout)         // [2][HID]: ws x1 for layer0, d_out (output) for layer1
{
    const int idx = (int)(blockIdx.x * blockDim.x + threadIdx.x); // 0..4095
    const int d = idx >> 11;       // direction
    const int j = idx & (HID - 1); // hidden unit

    const float* g = gates + d * G4H;
    float gi = g[j];
    float gf = g[HID + j];
    float gg = g[2 * HID + j];
    float go = g[3 * HID + j];

    float c_prev = c0[(size_t)(lo + d) * HID + j];
    float c2 = sigmoidf_(gf) * c_prev + sigmoidf_(gi) * tanhf(gg);
    float h2 = sigmoidf_(go) * tanhf(c2);

    hn[(size_t)(lo + d) * HID + j] = h2;
    cn[(size_t)(lo + d) * HID + j] = c2;
    xout[(size_t)d * HID + j] = h2;
}

extern "C" void kernel_launch(void* const* d_in, const int* in_sizes, int n_in,
                              void* d_out, int out_size, void* d_ws, size_t ws_size,
                              hipStream_t stream) {
    const int*   ids  = (const int*)  d_in[0];
    const float* h0   = (const float*)d_in[1];
    const float* c0   = (const float*)d_in[2];
    const float* emb  = (const float*)d_in[3];
    const float* Wih0 = (const float*)d_in[4];
    const float* Whh0 = (const float*)d_in[5];
    const float* bih0 = (const float*)d_in[6];
    const float* bhh0 = (const float*)d_in[7];
    const float* Wih1 = (const float*)d_in[8];
    const float* Whh1 = (const float*)d_in[9];
    const float* bih1 = (const float*)d_in[10];
    const float* bhh1 = (const float*)d_in[11];

    float* out   = (float*)d_out;          // [output(4096) | h_n(8192) | c_n(8192)]
    float* gates = (float*)d_ws;           // [2][8192] = 64 KB
    float* x1    = gates + 2 * G4H;        // [4096] = 16 KB

    // 16384 rows, 1 wave each, 4 waves/block -> 4096 blocks
    gates_kernel<1024><<<4096, 256, 0, stream>>>(emb, ids, Wih0, Whh0, bih0, bhh0, h0, 0, gates);
    cell_kernel<<<16, 256, 0, stream>>>(gates, c0, 0, out + 4096, out + 12288, x1);
    gates_kernel<4096><<<4096, 256, 0, stream>>>(x1, nullptr, Wih1, Whh1, bih1, bhh1, h0, 2, gates);
    cell_kernel<<<16, 256, 0, stream>>>(gates, c0, 2, out + 4096, out + 12288, out);
}

// Round 2
// 106.278 us; speedup vs baseline: 1.0154x; 1.0154x over previous
//
#include <hip/hip_runtime.h>

// EncoderRNN: 1-token, batch-1, bidirectional 2-layer LSTM. H=2048, EMB=1024.
// Memory-bound mat-vec (576 MB of fp32 weights read once). Structure:
//   phase1: L0 gates (Wih0*x + Whh0*h0, 192 MB) AND L1 Whh partial
//           (Whh1*h0 + biases, 128 MB) -- the latter depends only on inputs.
//   cell0 : L0 activations -> h_n/c_n rows 0,1 and x1 = [hf, hb]
//   phase2: L1 gates = Wih1*x1 (256 MB) + partial
//   cell1 : L1 activations -> h_n/c_n rows 2,3 and output
// One wave per gate row, float4 coalesced loads, shuffle reduce.

#define HID 2048
#define G4H 8192   // 4*HID rows per direction

__device__ __forceinline__ float wave_reduce_sum(float v) {
    #pragma unroll
    for (int off = 32; off > 0; off >>= 1)
        v += __shfl_down(v, off, 64);
    return v;
}

__global__ __launch_bounds__(256) void phase1_kernel(
    const int*   __restrict__ tok,
    const float* __restrict__ emb,    // [VOCAB][1024]
    const float* __restrict__ Wih0,   // [2][8192][1024]
    const float* __restrict__ Whh0,   // [2][8192][2048]
    const float* __restrict__ bih0,   // [2][8192]
    const float* __restrict__ bhh0,
    const float* __restrict__ Whh1,   // [2][8192][2048]
    const float* __restrict__ bih1,
    const float* __restrict__ bhh1,
    const float* __restrict__ h0,     // [4][2048]
    float* __restrict__ gates0,       // [2][8192]
    float* __restrict__ part1)        // [2][8192]  Whh1*h0 + bih1 + bhh1
{
    const int wave = (int)((blockIdx.x * blockDim.x + threadIdx.x) >> 6);
    const int lane = (int)(threadIdx.x & 63);

    if (wave < 2 * G4H) {
        // ---- layer 0 gate row ----
        const int dir = wave >> 13;
        const int r   = wave & (G4H - 1);
        const float*  x   = emb + (size_t)tok[0] * 1024;
        const float4* wih = (const float4*)(Wih0 + ((size_t)dir * G4H + r) * 1024);
        const float4* whh = (const float4*)(Whh0 + ((size_t)dir * G4H + r) * HID);
        const float4* xv  = (const float4*)x;
        const float4* hv  = (const float4*)(h0 + (size_t)dir * HID);

        float acc = 0.f;
        #pragma unroll
        for (int i = 0; i < 1024 / 4 / 64; ++i) {
            float4 w = wih[lane + i * 64], b = xv[lane + i * 64];
            acc += w.x * b.x + w.y * b.y + w.z * b.z + w.w * b.w;
        }
        #pragma unroll
        for (int i = 0; i < HID / 4 / 64; ++i) {
            float4 w = whh[lane + i * 64], b = hv[lane + i * 64];
            acc += w.x * b.x + w.y * b.y + w.z * b.z + w.w * b.w;
        }
        acc = wave_reduce_sum(acc);
        if (lane == 0) {
            int row = dir * G4H + r;
            gates0[row] = acc + bih0[row] + bhh0[row];
        }
    } else {
        // ---- layer 1 recurrent partial: Whh1*h0 + biases ----
        const int w2  = wave - 2 * G4H;
        const int dir = w2 >> 13;
        const int r   = w2 & (G4H - 1);
        const float4* whh = (const float4*)(Whh1 + ((size_t)dir * G4H + r) * HID);
        const float4* hv  = (const float4*)(h0 + (size_t)(2 + dir) * HID);

        float acc = 0.f;
        #pragma unroll
        for (int i = 0; i < HID / 4 / 64; ++i) {
            float4 w = whh[lane + i * 64], b = hv[lane + i * 64];
            acc += w.x * b.x + w.y * b.y + w.z * b.z + w.w * b.w;
        }
        acc = wave_reduce_sum(acc);
        if (lane == 0) {
            int row = dir * G4H + r;
            part1[row] = acc + bih1[row] + bhh1[row];
        }
    }
}

__global__ __launch_bounds__(256) void phase2_kernel(
    const float* __restrict__ x1,     // [4096]
    const float* __restrict__ Wih1,   // [2][8192][4096]
    const float* __restrict__ part1,  // [2][8192]
    float* __restrict__ gates)        // [2][8192]
{
    const int wave = (int)((blockIdx.x * blockDim.x + threadIdx.x) >> 6);
    const int lane = (int)(threadIdx.x & 63);
    const int dir  = wave >> 13;
    const int r    = wave & (G4H - 1);

    const float4* wih = (const float4*)(Wih1 + ((size_t)dir * G4H + r) * 4096);
    const float4* xv  = (const float4*)x1;

    float acc = 0.f;
    #pragma unroll
    for (int i = 0; i < 4096 / 4 / 64; ++i) {
        float4 w = wih[lane + i * 64], b = xv[lane + i * 64];
        acc += w.x * b.x + w.y * b.y + w.z * b.z + w.w * b.w;
    }
    acc = wave_reduce_sum(acc);
    if (lane == 0) {
        int row = dir * G4H + r;
        gates[row] = acc + part1[row];
    }
}

__device__ __forceinline__ float sigmoidf_(float v) {
    return 1.f / (1.f + expf(-v));
}

// PyTorch gate order i,f,g,o
__global__ __launch_bounds__(256) void cell_kernel(
    const float* __restrict__ gates,  // [2][8192] (biases included)
    const float* __restrict__ c0,     // [4][HID]
    int lo,                           // 0 (layer 0) or 2 (layer 1)
    float* __restrict__ hn,           // [4][HID]
    float* __restrict__ cn,           // [4][HID]
    float* __restrict__ xout)         // [2][HID]
{
    const int idx = (int)(blockIdx.x * blockDim.x + threadIdx.x); // 0..4095
    const int d = idx >> 11;
    const int j = idx & (HID - 1);

    const float* g = gates + d * G4H;
    float gi = g[j];
    float gf = g[HID + j];
    float gg = g[2 * HID + j];
    float go = g[3 * HID + j];

    float c_prev = c0[(size_t)(lo + d) * HID + j];
    float c2 = sigmoidf_(gf) * c_prev + sigmoidf_(gi) * tanhf(gg);
    float h2 = sigmoidf_(go) * tanhf(c2);

    hn[(size_t)(lo + d) * HID + j] = h2;
    cn[(size_t)(lo + d) * HID + j] = c2;
    xout[(size_t)d * HID + j] = h2;
}

extern "C" void kernel_launch(void* const* d_in, const int* in_sizes, int n_in,
                              void* d_out, int out_size, void* d_ws, size_t ws_size,
                              hipStream_t stream) {
    const int*   ids  = (const int*)  d_in[0];
    const float* h0   = (const float*)d_in[1];
    const float* c0   = (const float*)d_in[2];
    const float* emb  = (const float*)d_in[3];
    const float* Wih0 = (const float*)d_in[4];
    const float* Whh0 = (const float*)d_in[5];
    const float* bih0 = (const float*)d_in[6];
    const float* bhh0 = (const float*)d_in[7];
    const float* Wih1 = (const float*)d_in[8];
    const float* Whh1 = (const float*)d_in[9];
    const float* bih1 = (const float*)d_in[10];
    const float* bhh1 = (const float*)d_in[11];

    float* out    = (float*)d_out;        // [output(4096) | h_n(8192) | c_n(8192)]
    float* gates  = (float*)d_ws;         // [2][8192]
    float* part1  = gates + 2 * G4H;      // [2][8192]
    float* x1     = part1 + 2 * G4H;      // [4096]

    // phase1: 32768 waves (16384 L0 rows + 16384 L1-Whh rows), 4 waves/block
    phase1_kernel<<<8192, 256, 0, stream>>>(ids, emb, Wih0, Whh0, bih0, bhh0,
                                            Whh1, bih1, bhh1, h0, gates, part1);
    cell_kernel<<<16, 256, 0, stream>>>(gates, c0, 0, out + 4096, out + 12288, x1);
    // phase2: 16384 waves (L1 rows)
    phase2_kernel<<<4096, 256, 0, stream>>>(x1, Wih1, part1, gates);
    cell_kernel<<<16, 256, 0, stream>>>(gates, c0, 2, out + 4096, out + 12288, out);
}